// Round 1
// baseline (59.032 us; speedup 1.0000x reference)
//
#include <hip/hip_runtime.h>

// Closed form derived from the circuit:
//   Product state per qubit: |psi_q> = RZ(lam_q) RY(th_q) RX(pi*x_q) |0>
//   Observable ZZZZ conjugated through CX(0,1), CX(2,3) -> Z1 (x) Z3
//   RZ is diagonal -> no effect on computational-basis probabilities.
//   <Z>_q = cos(theta[q]) * cos(pi * x_q)
//   out[b] = cos(theta[1]) * cos(theta[3]) * cospi(x[b,1]) * cospi(x[b,3])

__global__ __launch_bounds__(256) void qlayer_expect(
    const float4* __restrict__ x,      // [B] rows of 4 floats
    const float* __restrict__ theta,   // [8]
    float* __restrict__ out,           // [B]
    int B)
{
    int i = blockIdx.x * 256 + threadIdx.x;
    if (i >= B) return;
    // theta is uniform across lanes; indices are compile-time constants ->
    // compiler emits scalar loads; cos of a near-zero angle, negligible cost.
    float scale = cosf(theta[1]) * cosf(theta[3]);
    float4 r = x[i];                   // coalesced 16B/lane
    out[i] = scale * cospif(r.y) * cospif(r.w);
}

extern "C" void kernel_launch(void* const* d_in, const int* in_sizes, int n_in,
                              void* d_out, int out_size, void* d_ws, size_t ws_size,
                              hipStream_t stream) {
    const float4* x     = (const float4*)d_in[0];   // [B,4] f32
    const float*  theta = (const float*)d_in[1];    // [8] f32
    float*        out   = (float*)d_out;            // [B,1] f32
    int B = in_sizes[0] / 4;
    int blocks = (B + 255) / 256;
    qlayer_expect<<<blocks, 256, 0, stream>>>(x, theta, out, B);
}